// Round 3
// baseline (492.241 us; speedup 1.0000x reference)
//
#include <hip/hip_runtime.h>
#include <hip/hip_bf16.h>

// Trellis-walk LUT dequant: out[r][c] = 0.011 * sign_l[r] * sign_r[c] *
//   lut[ walks[(r/16)*512 + c/16][ ((r%16)*16 + (c%16)) >> 1 ] ][ c & 1 ]
//
// Device layout facts (established R0-R2):
//   - walks is INT32 on device (harness converts integer inputs; the int64
//     read in R2 faulted at 2x the buffer extent).
//   - out is FLOAT32 (reference output dtype; R1's bf16 write produced the
//     packed-pair absmax signature).
//
// One thread = one 16-column tile-row segment:
//   - 8 contiguous int32 walk indices (32 B, 2x dwordx4; lane stride 512 B)
//   - 8 random float2 LUT gathers (lut is 512 KB -> L2-resident)
//   - 16 f32 outputs (64 B, 4x dwordx4; wave writes 4 KB contiguous)
__global__ __launch_bounds__(256) void trellis_dequant(
    const int* __restrict__ walks,      // (262144, 128) int32, values < 2^16
    const float* __restrict__ lut,      // (65536, 2)
    const float* __restrict__ sign_l,   // (8192,)
    const float* __restrict__ sign_r,   // (8192,)
    float* __restrict__ out)            // (8192, 8192) float32
{
    const int tid = blockIdx.x * 256 + threadIdx.x;
    const int r  = tid >> 9;            // output row (8192 rows, 512 threads/row)
    const int tc = tid & 511;           // tile column
    const int i  = r & 15;              // row within tile
    const int tr = r >> 4;              // tile row
    const size_t t = (size_t)tr * 512 + (size_t)tc;

    // 8 walk steps for this tile row: s = i*8 .. i*8+7
    const int4* wp = (const int4*)(walks + t * 128 + i * 8);
    const int4 a = wp[0];
    const int4 b = wp[1];

    const float2* lut2 = (const float2*)lut;
    const float2 v0 = lut2[a.x];
    const float2 v1 = lut2[a.y];
    const float2 v2 = lut2[a.z];
    const float2 v3 = lut2[a.w];
    const float2 v4 = lut2[b.x];
    const float2 v5 = lut2[b.y];
    const float2 v6 = lut2[b.z];
    const float2 v7 = lut2[b.w];

    const float sl = 0.011f * sign_l[r];
    const float4* srp = (const float4*)(sign_r + tc * 16);
    const float4 s0 = srp[0];
    const float4 s1 = srp[1];
    const float4 s2 = srp[2];
    const float4 s3 = srp[3];

    float4 o0, o1, o2, o3;
    o0.x = v0.x * (sl * s0.x);
    o0.y = v0.y * (sl * s0.y);
    o0.z = v1.x * (sl * s0.z);
    o0.w = v1.y * (sl * s0.w);
    o1.x = v2.x * (sl * s1.x);
    o1.y = v2.y * (sl * s1.y);
    o1.z = v3.x * (sl * s1.z);
    o1.w = v3.y * (sl * s1.w);
    o2.x = v4.x * (sl * s2.x);
    o2.y = v4.y * (sl * s2.y);
    o2.z = v5.x * (sl * s2.z);
    o2.w = v5.y * (sl * s2.w);
    o3.x = v6.x * (sl * s3.x);
    o3.y = v6.y * (sl * s3.y);
    o3.z = v7.x * (sl * s3.z);
    o3.w = v7.y * (sl * s3.w);

    float4* op = (float4*)(out + (size_t)r * 8192 + (size_t)tc * 16);
    op[0] = o0;
    op[1] = o1;
    op[2] = o2;
    op[3] = o3;
}

extern "C" void kernel_launch(void* const* d_in, const int* in_sizes, int n_in,
                              void* d_out, int out_size, void* d_ws, size_t ws_size,
                              hipStream_t stream) {
    const int*   walks  = (const int*)d_in[0];
    const float* lut    = (const float*)d_in[1];
    const float* sign_l = (const float*)d_in[2];
    const float* sign_r = (const float*)d_in[3];
    float* out = (float*)d_out;

    // 8192 rows * 512 tile-segments = 4,194,304 threads = 16384 blocks x 256
    trellis_dequant<<<16384, 256, 0, stream>>>(walks, lut, sign_l, sign_r, out);
}